// Round 11
// baseline (493.451 us; speedup 1.0000x reference)
//
#include <hip/hip_runtime.h>

using s8 = __attribute__((ext_vector_type(8))) short;
using f4 = __attribute__((ext_vector_type(4))) float;

constexpr int WIDTH   = 16;
constexpr int HID     = 512;
constexpr int NHEADS  = 8;
constexpr int DK      = 64;
constexpr int NLAYERS = 2;
constexpr int NHW     = 2;
constexpr int B       = 4;
constexpr int S       = 1024;
constexpr int PAD     = S + 2 * WIDTH;   // 1056
constexpr int RS      = 1024;            // split row width (shorts): [H(512)|L(512)]
constexpr int K2      = 1024;            // virtual K: A=[H|L], B=[H|H] (drops Ah*Bl)

// ---------------------------------------------------------------------------
// CHUNKED-FRAGMENT layout for all split-bf16 operand buffers.
// chunk (rg, kc) = 16 rows x 32 K-shorts = 512 shorts = 1 KB, lane-ordered:
//   element (row, col) -> chunk(row>>4, col>>5), in-chunk offset
//   (row&15)*8 + ((col>>3)&3)*128 + (col&7)   [= lane(fr,q)*8 + e]
// ---------------------------------------------------------------------------
__device__ inline size_t caddr(int row, int col) {
    return ((size_t)((row >> 4) * 32 + (col >> 5)) << 9)
         + ((row & 15) << 3) + (((col >> 3) & 3) << 7) + (col & 7);
}

__device__ inline unsigned short f2bf(float x) {
    union { float f; unsigned u; } c; c.f = x;
    unsigned r = c.u + 0x7fffu + ((c.u >> 16) & 1u);
    return (unsigned short)(r >> 16);
}
__device__ inline float bf2f(unsigned short h) {
    union { float f; unsigned u; } c; c.u = ((unsigned)h) << 16; return c.f;
}
__device__ inline void split2(float x, unsigned short& h, unsigned short& l) {
    h = f2bf(x);
    l = f2bf(x - bf2f(h));
}
// 8 consecutive cols (col%8==0) of one row -> one 16B h-frag + one 16B l-frag
__device__ inline void store_split8(unsigned short* base, int row, int col,
                                    float4 v0, float4 v1) {
    float v[8] = {v0.x, v0.y, v0.z, v0.w, v1.x, v1.y, v1.z, v1.w};
    unsigned h[4], l[4];
    #pragma unroll
    for (int j = 0; j < 4; ++j) {
        unsigned short h0, l0, h1, l1;
        split2(v[2 * j], h0, l0); split2(v[2 * j + 1], h1, l1);
        h[j] = h0 | ((unsigned)h1 << 16);
        l[j] = l0 | ((unsigned)l1 << 16);
    }
    *(uint4*)(base + caddr(row, col))       = make_uint4(h[0], h[1], h[2], h[3]);
    *(uint4*)(base + caddr(row, col + 512)) = make_uint4(l[0], l[1], l[2], l[3]);
}
// 4-col variant (col%4==0): 4 shorts contiguous within an 8-col block
__device__ inline void store_split4_c(unsigned short* base, int row, int col,
                                      float4 v) {
    unsigned short h[4], l[4];
    split2(v.x, h[0], l[0]); split2(v.y, h[1], l[1]);
    split2(v.z, h[2], l[2]); split2(v.w, h[3], l[3]);
    uint2 hp, lp;
    hp.x = h[0] | ((unsigned)h[1] << 16); hp.y = h[2] | ((unsigned)h[3] << 16);
    lp.x = l[0] | ((unsigned)l[1] << 16); lp.y = l[2] | ((unsigned)l[3] << 16);
    *(uint2*)(base + caddr(row, col))       = hp;
    *(uint2*)(base + caddr(row, col + 512)) = lp;
}

// bijective XCD-aware block swizzle (m204): contiguous grid bands per XCD
__device__ inline void xcd_swizzle(int& bx, int& by) {
    const int gx = gridDim.x, gy = gridDim.y;
    const int nwg = gx * gy;
    const int orig = by * gx + bx;
    const int q = nwg >> 3, r = nwg & 7;
    const int x8 = orig & 7, i8 = orig >> 3;
    const int wg = (x8 < r ? x8 * (q + 1) : r * (q + 1) + (x8 - r) * q) + i8;
    bx = wg % gx;
    by = wg / gx;
}
// 1-D variant for grids with gridDim.x % 8 == 0: XCD x gets the contiguous
// band [x*n/8, (x+1)*n/8) of work ids -> neighbor blocks (which share K/V or
// tap rows) land on the SAME XCD's L2.
__device__ inline int xcd_swizzle1(int bid, int n) {
    const int q = n >> 3;
    return (bid & 7) * q + (bid >> 3);
}

// ---------------------------------------------------------------------------
__global__ __launch_bounds__(256) void build_pad_split(
    const float* __restrict__ src0, const float* __restrict__ src1,
    const float* __restrict__ front, const float* __restrict__ back,
    unsigned short* __restrict__ d0, unsigned short* __restrict__ d1)
{
    const float* x = blockIdx.z ? src1 : src0;
    unsigned short* xp2 = blockIdx.z ? d1 : d0;
    int idx = blockIdx.x * 256 + threadIdx.x;   // over B*PAD*64
    int c8 = idx & 63;
    int rest = idx >> 6;
    int p = rest % PAD;
    int b = rest / PAD;
    const float* s;
    if (p < WIDTH) {
        s = front + (size_t)p * HID;
    } else if (p < WIDTH + S) {
        s = x + ((size_t)b * S + (p - WIDTH)) * HID;
    } else {
        s = back + (size_t)(p - WIDTH - S) * HID;
    }
    float4 v0 = *(const float4*)(s + c8 * 8);
    float4 v1 = *(const float4*)(s + c8 * 8 + 4);
    store_split8(xp2, b * PAD + p, c8 * 8, v0, v1);
}

// ---------------------------------------------------------------------------
// per-use weight conversion (fallback paths): fp32 [R,HID] -> chunked split
// ---------------------------------------------------------------------------
__global__ __launch_bounds__(256) void conv_w(
    const float* __restrict__ s0, const float* __restrict__ s1,
    unsigned short* __restrict__ w0, unsigned short* __restrict__ w1)
{
    const float* src = blockIdx.z ? s1 : s0;
    unsigned short* dst = blockIdx.z ? w1 : w0;
    int idx = blockIdx.x * 256 + threadIdx.x;   // over R*64
    int c8 = idx & 63;
    int r  = idx >> 6;
    float4 v0 = *(const float4*)(src + (size_t)r * HID + c8 * 8);
    float4 v1 = *(const float4*)(src + (size_t)r * HID + c8 * 8 + 4);
    store_split8(dst, r, c8 * 8, v0, v1);
}

// ---------------------------------------------------------------------------
// one-shot conversion of ALL weights -> w2all [2 dirs][8192 rows] chunked.
// ---------------------------------------------------------------------------
__global__ __launch_bounds__(256) void conv_all(
    const float* __restrict__ fw_lin_w, const float* __restrict__ bw_lin_w,
    const float* __restrict__ fw_hw_w,  const float* __restrict__ bw_hw_w,
    unsigned short* __restrict__ w2all)
{
    int idx = blockIdx.x * 256 + threadIdx.x;   // over 8192*64
    int c8 = idx & 63;
    int r  = idx >> 6;          // 0..8191
    int l  = r >> 12;           // layer
    int rr = r & 4095;
    const float* lin = blockIdx.z ? bw_lin_w : fw_lin_w;
    const float* hw  = blockIdx.z ? bw_hw_w  : fw_hw_w;
    const float* src;
    int drow;
    if (rr < 2048) {
        src  = lin + ((size_t)l * 2048 + rr) * HID;
        drow = blockIdx.z * 8192 + l * 4096 + rr;
    } else {
        int sub  = rr - 2048;
        int i_hw = sub >> 10;
        int rr2  = sub & 1023;
        int c    = rr2 & 511;
        int is_g = rr2 >> 9;
        int p    = ((c >> 4) << 5) + (c & 15) + (is_g << 4);
        src  = hw + ((size_t)l * 2048 + sub) * HID;
        drow = blockIdx.z * 8192 + l * 4096 + 2048 + (i_hw << 10) + p;
    }
    float4 v0 = *(const float4*)(src + c8 * 8);
    float4 v1 = *(const float4*)(src + c8 * 8 + 4);
    store_split8(w2all, drow, c8 * 8, v0, v1);
}

// ===========================================================================
// HYBRID split-bf16 MFMA GEMM (NT), chunked operands (R6/R8-proven core),
// MIXED-DEPTH rings: A via LDS 4-slot ring at distance 3 (LDS is free —
// no register cost, unlike R9's spilling ring-4), B direct-to-register
// 3-slot ring at distance 2 (B is L1-hot; R9 proved deeper B rings spill).
// Per iter t: wait vmcnt(8) [outstanding = A(t+1),A(t+2),B(t+1) = 8 ops ->
// certifies A(t),B(t)] -> s_barrier -> issue stageA(t+3) + loadB(t+2) ->
// 8 ds_read + 16 MFMA. Tail: t=30 -> vmcnt(6), t=31 -> vmcnt(0).
// Race: slot (t+3)&3 last read at t-1; reads consumed before t-1's MFMAs,
// which precede the barrier at top of t (same argument as ring-3).
// LDS 32KB, 3 blocks/CU; VGPR unchanged vs R8 (spill falsifier: FETCH/WRITE
// must stay ~39.5/54.7MB).
// ===========================================================================
#define GLDS(src, dst) __builtin_amdgcn_global_load_lds(                        \
    (const __attribute__((address_space(1))) void*)(src),                       \
    (__attribute__((address_space(3))) void*)(dst), 16, 0, 0)

#define GEMM_CORE                                                               \
    __shared__ unsigned short Als[4][8 * 512];                                  \
    const int tid  = threadIdx.x;                                               \
    const int wave = tid >> 6;                                                  \
    const int lane = tid & 63;                                                  \
    int bx = blockIdx.x, by = blockIdx.y;                                       \
    xcd_swizzle(bx, by);                                                        \
    const int bm = by * 128;                                                    \
    const int bn = bx * 128;                                                    \
    const int wm = (wave >> 1) * 64;                                            \
    const int wn = (wave & 1) * 64;                                             \
    const unsigned short* SA0 = A  + ((size_t)((bm >> 4) + 2 * wave)     << 14) \
                                   + lane * 8;                                  \
    const unsigned short* SA1 = A  + ((size_t)((bm >> 4) + 2 * wave + 1) << 14) \
                                   + lane * 8;                                  \
    const unsigned short* pb[4];                                                \
    _Pragma("unroll")                                                           \
    for (int j = 0; j < 4; ++j)                                                 \
        pb[j] = Bw + ((size_t)((((bn + wn) >> 4) + j) * 32) << 9) + lane * 8;   \
    f4 acc[4][4] = {};                                                          \
    s8 bfr[3][4];                                                               \
    auto stageA = [&](int slot, int kt) {                                       \
        const int ao = kt << 9;                                                 \
        GLDS(SA0 + ao, &Als[slot][(2 * wave)     * 512]);                       \
        GLDS(SA1 + ao, &Als[slot][(2 * wave + 1) * 512]);                       \
    };                                                                          \
    auto loadB = [&](int slot, int kt) {                                        \
        const int bo = (kt & 15) << 9;                                          \
        _Pragma("unroll")                                                       \
        for (int j = 0; j < 4; ++j)                                             \
            bfr[slot][j] = *(const s8*)(pb[j] + bo);                            \
    };                                                                          \
    stageA(0, 0); loadB(0, 0);                                                  \
    stageA(1, 1); loadB(1, 1);                                                  \
    stageA(2, 2);                                                               \
    _Pragma("unroll")                                                           \
    for (int t = 0; t < 32; ++t) {                                              \
        if (t == 31)      asm volatile("s_waitcnt vmcnt(0)" ::: "memory");      \
        else if (t == 30) asm volatile("s_waitcnt vmcnt(6)" ::: "memory");      \
        else              asm volatile("s_waitcnt vmcnt(8)" ::: "memory");      \
        __builtin_amdgcn_s_barrier();                                           \
        if (t < 29) stageA((t + 3) & 3, t + 3);                                 \
        if (t < 30) loadB((t + 2) % 3, t + 2);                                  \
        s8 a[4];                                                                \
        _Pragma("unroll")                                                       \
        for (int i = 0; i < 4; ++i)                                             \
            a[i] = *(const s8*)&Als[t & 3][((wave >> 1) * 4 + i) * 512 + lane * 8];\
        __builtin_amdgcn_s_setprio(1);                                          \
        _Pragma("unroll")                                                       \
        for (int i = 0; i < 4; ++i)                                             \
            _Pragma("unroll")                                                   \
            for (int j = 0; j < 4; ++j)                                         \
                acc[i][j] = __builtin_amdgcn_mfma_f32_16x16x32_bf16(            \
                    a[i], bfr[t % 3][j], acc[i][j], 0, 0, 0);                   \
        __builtin_amdgcn_s_setprio(0);                                          \
    }

__global__ __launch_bounds__(256, 3) void gemm_split(
    const unsigned short* __restrict__ A0, const unsigned short* __restrict__ B0,
    const float* __restrict__ bias0, float* __restrict__ C0,
    const unsigned short* __restrict__ A1, const unsigned short* __restrict__ B1,
    const float* __restrict__ bias1, float* __restrict__ C1,
    int N)
{
    const unsigned short* A  = blockIdx.z ? A1 : A0;
    const unsigned short* Bw = blockIdx.z ? B1 : B0;
    const float* bias        = blockIdx.z ? bias1 : bias0;
    float* C                 = blockIdx.z ? C1 : C0;

    GEMM_CORE

    const int col = lane & 15;
    const int rb  = (lane >> 4) * 4;
    #pragma unroll
    for (int j = 0; j < 4; ++j) {
        float bj = bias[bn + wn + j * 16 + col];
        #pragma unroll
        for (int i = 0; i < 4; ++i) {
            size_t base = (size_t)(bm + wm + i * 16 + rb) * N + (bn + wn + j * 16 + col);
            #pragma unroll
            for (int r = 0; r < 4; ++r)
                C[base + (size_t)r * N] = acc[i][j][r] + bj;
        }
    }
}

// ---------------------------------------------------------------------------
// Fused highway GEMM (wall path), same hybrid core. N=1024 permuted weights
// (nl/gate 16-col interleave). Epilogue applies gate; x read from A (chunked).
// ---------------------------------------------------------------------------
__global__ __launch_bounds__(256, 3) void gemm_hw_fused(
    const unsigned short* __restrict__ A0, const unsigned short* __restrict__ B0,
    const float* __restrict__ hwb0, unsigned short* __restrict__ o2_0,
    float* __restrict__ dst0, float* __restrict__ osl0,
    const unsigned short* __restrict__ A1, const unsigned short* __restrict__ B1,
    const float* __restrict__ hwb1, unsigned short* __restrict__ o2_1,
    float* __restrict__ dst1, float* __restrict__ osl1,
    int first)
{
    const unsigned short* A  = blockIdx.z ? A1 : A0;
    const unsigned short* Bw = blockIdx.z ? B1 : B0;
    const float* hwb         = blockIdx.z ? hwb1 : hwb0;
    unsigned short* o2       = blockIdx.z ? o2_1 : o2_0;
    float* dstf              = blockIdx.z ? dst1 : dst0;
    float* osl               = blockIdx.z ? osl1 : osl0;

    GEMM_CORE

    const int col = lane & 15;
    const int rb  = (lane >> 4) * 4;
    #pragma unroll
    for (int jp = 0; jp < 2; ++jp) {
        const int cc = ((bn + wn) >> 1) + jp * 16 + col;   // orig col 0..511
        const float bnl = hwb[cc];
        const float bg  = hwb[512 + cc];
        #pragma unroll
        for (int i = 0; i < 4; ++i) {
            #pragma unroll
            for (int r = 0; r < 4; ++r) {
                const int row = bm + wm + i * 16 + rb + r;
                float nl = acc[i][2 * jp][r] + bnl;
                float g  = acc[i][2 * jp + 1][r] + bg;
                float xv = bf2f(A[caddr(row, cc)])
                         + bf2f(A[caddr(row, cc + 512)]);
                float sg = 1.f / (1.f + __expf(-g));
                float o  = sg * xv + (1.f - sg) * fmaxf(nl, 0.f);
                if (first) {
                    unsigned short hh, ll; split2(o, hh, ll);
                    o2[caddr(row, cc)]       = hh;
                    o2[caddr(row, cc + 512)] = ll;
                } else {
                    dstf[(size_t)row * HID + cc]      = o;
                    osl[(size_t)row * (2 * HID) + cc] = o;
                }
            }
        }
    }
}

// ---------------------------------------------------------------------------
// Banded MHA, wave-parallel softmax+PV. One wave per (b,h,i).
// Lane (s = lane>>4, d = lane&15) owns taps {4m+s} and cols {4d..4d+3}.
// XCD band swizzle keeps consecutive i on one XCD's L2 (R8-proven).
// backward = dir0 + z.
// ---------------------------------------------------------------------------
__global__ __launch_bounds__(256) void banded_attn(
    const float* __restrict__ Q0, const float* __restrict__ Q1,
    unsigned short* __restrict__ O0, unsigned short* __restrict__ O1,
    int dir0)
{
    const float* QKV = blockIdx.z ? Q1 : Q0;
    unsigned short* O2 = blockIdx.z ? O1 : O0;
    int backward = dir0 + blockIdx.z;

    int wg   = xcd_swizzle1(blockIdx.x, gridDim.x);   // gridDim.x % 8 == 0
    int w    = wg * 4 + (threadIdx.x >> 6);
    int lane = threadIdx.x & 63;
    int i  = w % PAD;
    int bh = w / PAD;
    int h  = bh & (NHEADS - 1);
    int b  = bh / NHEADS;

    int jlo, n;
    if (backward) { jlo = i; n = min(WIDTH + 2, PAD - i); }
    else          { jlo = max(0, i - WIDTH - 1); n = i - jlo + 1; }

    const int s = lane >> 4;
    const int d = lane & 15;
    const size_t rowbase = (size_t)(b * PAD) * 1536;
    const int colq = h * DK;

    float4 q4 = *(const float4*)(QKV + rowbase + (size_t)i * 1536 + colq + 4 * d);

    // scores: lane's taps t = 4m+s; invalid taps masked to -1e30
    float sc[5];
    float mx = -1e30f;
    #pragma unroll
    for (int m = 0; m < 5; ++m) {
        int t  = 4 * m + s;
        int tc = t < n ? t : n - 1;
        float4 kv = *(const float4*)(QKV + rowbase + (size_t)(jlo + tc) * 1536
                                     + 512 + colq + 4 * d);
        float p = q4.x * kv.x + q4.y * kv.y + q4.z * kv.z + q4.w * kv.w;
        p += __shfl_xor(p, 1);
        p += __shfl_xor(p, 2);
        p += __shfl_xor(p, 4);
        p += __shfl_xor(p, 8);
        sc[m] = (t < n) ? p * 0.125f : -1e30f;
        mx = fmaxf(mx, sc[m]);
    }
    // global max over s-groups (d fixed)
    mx = fmaxf(mx, __shfl_xor(mx, 16));
    mx = fmaxf(mx, __shfl_xor(mx, 32));

    float e[5];
    float dsum = 0.f;
    #pragma unroll
    for (int m = 0; m < 5; ++m) { e[m] = __expf(sc[m] - mx); dsum += e[m]; }
    dsum += __shfl_xor(dsum, 16);
    dsum += __shfl_xor(dsum, 32);
    float inv = 1.0f / dsum;

    // PV: lane accumulates its taps' V rows (float4 over its col-quad)
    float4 pv = make_float4(0.f, 0.f, 0.f, 0.f);
    #pragma unroll
    for (int m = 0; m < 5; ++m) {
        int t  = 4 * m + s;
        int tc = t < n ? t : n - 1;
        float4 v4 = *(const float4*)(QKV + rowbase + (size_t)(jlo + tc) * 1536
                                     + 1024 + colq + 4 * d);
        pv.x += e[m] * v4.x; pv.y += e[m] * v4.y;
        pv.z += e[m] * v4.z; pv.w += e[m] * v4.w;
    }
    // reduce over s-groups
    pv.x += __shfl_xor(pv.x, 16); pv.y += __shfl_xor(pv.y, 16);
    pv.z += __shfl_xor(pv.z, 16); pv.w += __shfl_xor(pv.w, 16);
    pv.x += __shfl_xor(pv.x, 32); pv.y += __shfl_xor(pv.y, 32);
    pv.z += __shfl_xor(pv.z, 32); pv.w += __shfl_xor(pv.w, 32);

    if (s == 0) {
        float4 o = make_float4(pv.x * inv, pv.y * inv, pv.z * inv, pv.w * inv);
        store_split4_c(O2, b * PAD + i, colq + 4 * d, o);
    }
}

// ---------------------------------------------------------------------------
// rel_combine with the same XCD band swizzle (17 overlapping-row taps ->
// neighbor blocks share ATT rows; keep them on one XCD's L2).
// ---------------------------------------------------------------------------
__global__ __launch_bounds__(256) void rel_combine(
    const float* __restrict__ a0, const float* __restrict__ a1,
    const float* __restrict__ w0, const float* __restrict__ w1,
    unsigned short* __restrict__ f0, unsigned short* __restrict__ f1,
    int off0, int off1)
{
    const float* att = blockIdx.z ? a1 : a0;
    const float* w   = blockIdx.z ? w1 : w0;
    unsigned short* fo2 = blockIdx.z ? f1 : f0;
    int offset = blockIdx.z ? off1 : off0;

    int bid = xcd_swizzle1(blockIdx.x, gridDim.x);    // gridDim.x % 8 == 0
    int idx = bid * 256 + threadIdx.x;                // over B*S*64
    int c8 = idx & 63;
    int rest = idx >> 6;
    int t = rest & (S - 1);
    int b = rest >> 10;

    const float* rowbase = att + (size_t)b * PAD * HID + c8 * 8;
    float4 acc0 = *(const float4*)(rowbase + (size_t)(WIDTH + t) * HID);
    float4 acc1 = *(const float4*)(rowbase + (size_t)(WIDTH + t) * HID + 4);
    #pragma unroll
    for (int k = 0; k <= WIDTH; ++k) {
        float wk = w[k];
        float4 x0 = *(const float4*)(rowbase + (size_t)(offset + k + t) * HID);
        float4 x1 = *(const float4*)(rowbase + (size_t)(offset + k + t) * HID + 4);
        acc0.x += wk * x0.x; acc0.y += wk * x0.y;
        acc0.z += wk * x0.z; acc0.w += wk * x0.w;
        acc1.x += wk * x1.x; acc1.y += wk * x1.y;
        acc1.z += wk * x1.z; acc1.w += wk * x1.w;
    }
    store_split8(fo2, b * S + t, c8 * 8, acc0, acc1);
}

// ---------------------------------------------------------------------------
// standalone highway gate (non-wall fallback only)
// ---------------------------------------------------------------------------
__global__ __launch_bounds__(256) void highway_gate(
    const unsigned short* __restrict__ x0, const unsigned short* __restrict__ x1,
    const float* __restrict__ p0, const float* __restrict__ p1,
    float* __restrict__ of0, float* __restrict__ of1,
    unsigned short* __restrict__ o20, unsigned short* __restrict__ o21,
    float* __restrict__ os0, float* __restrict__ os1)
{
    const unsigned short* x2 = blockIdx.z ? x1 : x0;
    const float* proj        = blockIdx.z ? p1 : p0;
    float* outf              = blockIdx.z ? of1 : of0;
    unsigned short* out2     = blockIdx.z ? o21 : o20;
    float* oslice            = blockIdx.z ? os1 : os0;

    int idx = blockIdx.x * 256 + threadIdx.x;   // over B*S*128
    int c4 = idx & 127;
    int r  = idx >> 7;
    uint2 hp = *(const uint2*)(x2 + caddr(r, c4 * 4));
    uint2 lp = *(const uint2*)(x2 + caddr(r, c4 * 4 + 512));
    float4 xv;
    xv.x = bf2f((unsigned short)(hp.x & 0xffff)) + bf2f((unsigned short)(lp.x & 0xffff));
    xv.y = bf2f((unsigned short)(hp.x >> 16))    + bf2f((unsigned short)(lp.x >> 16));
    xv.z = bf2f((unsigned short)(hp.y & 0xffff)) + bf2f((unsigned short)(lp.y & 0xffff));
    xv.w = bf2f((unsigned short)(hp.y >> 16))    + bf2f((unsigned short)(lp.y >> 16));

    float4 nl = *(const float4*)(proj + (size_t)r * (2 * HID) + c4 * 4);
    float4 g  = *(const float4*)(proj + (size_t)r * (2 * HID) + HID + c4 * 4);
    float4 o;
    float sg;
    sg = 1.f / (1.f + __expf(-g.x)); o.x = sg * xv.x + (1.f - sg) * fmaxf(nl.x, 0.f);
    sg = 1.f / (1.f + __expf(-g.y)); o.y = sg * xv.y + (1.f - sg) * fmaxf(nl.y, 0.f);
    sg = 1.f / (1.f + __expf(-g.z)); o.z = sg * xv.z + (1.f - sg) * fmaxf(nl.z, 0.f);
    sg = 1.f / (1.f + __expf(-g.w)); o.w = sg * xv.w + (1.f - sg) * fmaxf(nl.w, 0.f);
    if (outf)   *(float4*)(outf + (size_t)idx * 4) = o;
    if (out2)   store_split4_c(out2, r, c4 * 4, o);
    if (oslice) *(float4*)(oslice + (size_t)r * (2 * HID) + c4 * 4) = o;
}

// ---------------------------------------------------------------------------
extern "C" void kernel_launch(void* const* d_in, const int* in_sizes, int n_in,
                              void* d_out, int out_size, void* d_ws, size_t ws_size,
                              hipStream_t stream)
{
    const float* inputs   = (const float*)d_in[0];
    const float* fw_lin_w = (const float*)d_in[2];
    const float* fw_lin_b = (const float*)d_in[3];
    const float* bw_lin_w = (const float*)d_in[4];
    const float* bw_lin_b = (const float*)d_in[5];
    const float* fw_hw_w  = (const float*)d_in[6];
    const float* fw_hw_b  = (const float*)d_in[7];
    const float* bw_hw_w  = (const float*)d_in[8];
    const float* bw_hw_b  = (const float*)d_in[9];
    const float* fw_pad   = (const float*)d_in[10];
    const float* bw_pad   = (const float*)d_in[11];
    const float* fw_rel   = (const float*)d_in[12];
    const float* bw_rel   = (const float*)d_in[13];
    float* out = (float*)d_out;
    float* ws  = (float*)d_ws;

    const size_t BSH  = (size_t)B * S * HID;      // 2,097,152 floats
    const size_t QKVF = (size_t)B * PAD * 1536;   // 6,488,064 floats per dir
    const int MP = B * PAD;                       // 4224 (= 33 * 128, 264*16)
    const int MS = B * S;                         // 4096 (= 32 * 128)

    const size_t GROUPED_FLOATS = 2 * QKVF + (2 * (size_t)MP * RS + 2 * (size_t)1536 * RS) / 2;
    const size_t WALL_FLOATS    = 2 * QKVF + (2 * (size_t)MP * RS + (size_t)2 * 8192 * RS) / 2;
    const bool wall    = ws_size >= WALL_FLOATS * 4;
    const bool grouped = wall || ws_size >= GROUPED_FLOATS * 4;
    const int G = grouped ? 2 : 1;

    float* f  = ws;
    float* bk = f + BSH;

    float* QKV[2]; float* ATT[2]; float* HWP[2];
    unsigned short* ACT2[2]; unsigned short* W2[2];
    unsigned short* ACT2B[2] = {nullptr, nullptr};
    unsigned short* w2all = nullptr;
    if (grouped) {
        QKV[0] = ws;             QKV[1] = ws + QKVF;
        float* extra = ws + 2 * BSH;
        ATT[0] = extra;          ATT[1] = extra + (size_t)MP * HID;
        HWP[0] = extra;          HWP[1] = extra + (size_t)MS * 1024;
        // ping buffer for fused hw (aliases ATT/HWP region; dead by hw phase)
        ACT2B[0] = (unsigned short*)extra;
        ACT2B[1] = ACT2B[0] + (size_t)MS * RS;
        unsigned short* a2 = (unsigned short*)(ws + 2 * QKVF);
        ACT2[0] = a2;            ACT2[1] = a2 + (size_t)MP * RS;
        unsigned short* w2 = a2 + 2 * (size_t)MP * RS;
        if (wall) { w2all = w2; W2[0] = W2[1] = nullptr; }
        else      { W2[0] = w2; W2[1] = w2 + (size_t)1536 * RS; }
    } else {
        float* qkvS = bk + BSH;
        QKV[0] = QKV[1] = qkvS;
        ATT[0] = ATT[1] = qkvS;
        HWP[0] = HWP[1] = qkvS;
        unsigned short* a2 = (unsigned short*)(qkvS + QKVF);
        ACT2[0] = ACT2[1] = a2;
        W2[0] = W2[1] = a2 + (size_t)MP * RS;
    }

    if (wall) {
        conv_all<<<dim3(8192 * 64 / 256, 1, 2), 256, 0, stream>>>(
            fw_lin_w, bw_lin_w, fw_hw_w, bw_hw_w, w2all);
    }
    // w2all row offsets per (dir,l): QKV=0, out=1536, hw_i=2048+1024*i
    // (all multiples of 16 rows -> chunked sub-buffer offset == row*RS)
    auto WB = [&](int dir, int l, int seg) -> unsigned short* {
        return w2all + ((size_t)dir * 8192 + (size_t)l * 4096 + seg) * RS;
    };

    for (int l = 0; l < NLAYERS; ++l) {
        const float* LINW[2] = {fw_lin_w + (size_t)l * 4 * HID * HID,
                                bw_lin_w + (size_t)l * 4 * HID * HID};
        const float* LINB[2] = {fw_lin_b + (size_t)l * 4 * HID,
                                bw_lin_b + (size_t)l * 4 * HID};
        const float* HWW[2]  = {fw_hw_w + (size_t)l * NHW * 2 * HID * HID,
                                bw_hw_w + (size_t)l * NHW * 2 * HID * HID};
        const float* HWB[2]  = {fw_hw_b + (size_t)l * NHW * 2 * HID,
                                bw_hw_b + (size_t)l * NHW * 2 * HID};
        const float* RELW[2] = {fw_rel + (size_t)l * (WIDTH + 1),
                                bw_rel + (size_t)l * (WIDTH + 1)};
        const float* front = fw_pad + (size_t)l * WIDTH * HID;
        const float* back  = bw_pad + (size_t)l * WIDTH * HID;
        float* DST[2] = {f, bk};
        float* OSL[2] = {out + (size_t)l * B * S * 2 * HID,
                         out + (size_t)l * B * S * 2 * HID + HID};
        const float* SRC[2] = {(l == 0) ? inputs : f, (l == 0) ? inputs : bk};

        for (int d0 = 0; d0 < 2; d0 += G) {
            const int dB = (G == 2) ? 1 : d0;

            build_pad_split<<<dim3(MP * 64 / 256, 1, G), 256, 0, stream>>>(
                SRC[d0], SRC[dB], front, back, ACT2[0], ACT2[1]);

            unsigned short *wq0, *wq1;
            if (wall) { wq0 = WB(d0, l, 0); wq1 = WB(dB, l, 0); }
            else {
                conv_w<<<dim3(1536 * 64 / 256, 1, G), 256, 0, stream>>>(
                    LINW[d0], LINW[dB], W2[0], W2[1]);
                wq0 = W2[0]; wq1 = W2[1];
            }
            gemm_split<<<dim3(1536 / 128, MP / 128, G), 256, 0, stream>>>(
                ACT2[0], wq0, LINB[d0], QKV[0],
                ACT2[1], wq1, LINB[dB], QKV[1], 1536);

            banded_attn<<<dim3(B * NHEADS * PAD / 4, 1, G), 256, 0, stream>>>(
                QKV[0], QKV[1], ACT2[0], ACT2[1], d0);

            unsigned short *wo0, *wo1;
            if (wall) { wo0 = WB(d0, l, 1536); wo1 = WB(dB, l, 1536); }
            else {
                conv_w<<<dim3(512 * 64 / 256, 1, G), 256, 0, stream>>>(
                    LINW[d0] + 3 * (size_t)HID * HID, LINW[dB] + 3 * (size_t)HID * HID,
                    W2[0], W2[1]);
                wo0 = W2[0]; wo1 = W2[1];
            }
            gemm_split<<<dim3(512 / 128, MP / 128, G), 256, 0, stream>>>(
                ACT2[0], wo0, LINB[d0] + 3 * HID, ATT[0],
                ACT2[1], wo1, LINB[dB] + 3 * HID, ATT[1], 512);

            rel_combine<<<dim3(MS * 64 / 256, 1, G), 256, 0, stream>>>(
                ATT[0], ATT[1], RELW[d0], RELW[dB], ACT2[0], ACT2[1],
                d0 * WIDTH, dB * WIDTH);

            if (wall) {
                // hw0: act2 -> act2b (ping), gate fused
                gemm_hw_fused<<<dim3(1024 / 128, MS / 128, G), 256, 0, stream>>>(
                    ACT2[0], WB(d0, l, 2048), HWB[d0], ACT2B[0], nullptr, nullptr,
                    ACT2[1], WB(dB, l, 2048), HWB[dB], ACT2B[1], nullptr, nullptr, 1);
                // hw1: act2b -> dst + output slice, gate fused
                gemm_hw_fused<<<dim3(1024 / 128, MS / 128, G), 256, 0, stream>>>(
                    ACT2B[0], WB(d0, l, 3072), HWB[d0] + 1024, nullptr, DST[d0], OSL[d0],
                    ACT2B[1], WB(dB, l, 3072), HWB[dB] + 1024, nullptr, DST[dB], OSL[dB], 0);
            } else {
                for (int i = 0; i < NHW; ++i) {
                    conv_w<<<dim3(1024 * 64 / 256, 1, G), 256, 0, stream>>>(
                        HWW[d0] + (size_t)i * 2 * HID * HID,
                        HWW[dB] + (size_t)i * 2 * HID * HID, W2[0], W2[1]);
                    gemm_split<<<dim3(1024 / 128, MS / 128, G), 256, 0, stream>>>(
                        ACT2[0], W2[0], HWB[d0] + (size_t)i * 2 * HID, HWP[0],
                        ACT2[1], W2[1], HWB[dB] + (size_t)i * 2 * HID, HWP[1], 1024);
                    const bool last = (i == NHW - 1);
                    highway_gate<<<dim3(MS * 128 / 256, 1, G), 256, 0, stream>>>(
                        ACT2[0], ACT2[1], HWP[0], HWP[1],
                        last ? DST[d0] : (float*)nullptr,
                        last ? DST[dB] : (float*)nullptr,
                        last ? (unsigned short*)nullptr : ACT2[0],
                        last ? (unsigned short*)nullptr : ACT2[1],
                        last ? OSL[d0] : (float*)nullptr,
                        last ? OSL[dB] : (float*)nullptr);
                }
            }
        }
    }
}

// Round 12
// 472.838 us; speedup vs baseline: 1.0436x; 1.0436x over previous
//
#include <hip/hip_runtime.h>

using s8 = __attribute__((ext_vector_type(8))) short;
using f4 = __attribute__((ext_vector_type(4))) float;

constexpr int WIDTH   = 16;
constexpr int HID     = 512;
constexpr int NHEADS  = 8;
constexpr int DK      = 64;
constexpr int NLAYERS = 2;
constexpr int NHW     = 2;
constexpr int B       = 4;
constexpr int S       = 1024;
constexpr int PAD     = S + 2 * WIDTH;   // 1056
constexpr int RS      = 1024;            // split row width (shorts): [H(512)|L(512)]
constexpr int K2      = 1024;            // virtual K: A=[H|L], B=[H|H] (drops Ah*Bl)

// ---------------------------------------------------------------------------
// CHUNKED-FRAGMENT layout for all split-bf16 operand buffers.
// chunk (rg, kc) = 16 rows x 32 K-shorts = 512 shorts = 1 KB, lane-ordered:
//   element (row, col) -> chunk(row>>4, col>>5), in-chunk offset
//   (row&15)*8 + ((col>>3)&3)*128 + (col&7)   [= lane(fr,q)*8 + e]
// ---------------------------------------------------------------------------
__device__ inline size_t caddr(int row, int col) {
    return ((size_t)((row >> 4) * 32 + (col >> 5)) << 9)
         + ((row & 15) << 3) + (((col >> 3) & 3) << 7) + (col & 7);
}

__device__ inline unsigned short f2bf(float x) {
    union { float f; unsigned u; } c; c.f = x;
    unsigned r = c.u + 0x7fffu + ((c.u >> 16) & 1u);
    return (unsigned short)(r >> 16);
}
__device__ inline float bf2f(unsigned short h) {
    union { float f; unsigned u; } c; c.u = ((unsigned)h) << 16; return c.f;
}
__device__ inline void split2(float x, unsigned short& h, unsigned short& l) {
    h = f2bf(x);
    l = f2bf(x - bf2f(h));
}
// 8 consecutive cols (col%8==0) of one row -> one 16B h-frag + one 16B l-frag
__device__ inline void store_split8(unsigned short* base, int row, int col,
                                    float4 v0, float4 v1) {
    float v[8] = {v0.x, v0.y, v0.z, v0.w, v1.x, v1.y, v1.z, v1.w};
    unsigned h[4], l[4];
    #pragma unroll
    for (int j = 0; j < 4; ++j) {
        unsigned short h0, l0, h1, l1;
        split2(v[2 * j], h0, l0); split2(v[2 * j + 1], h1, l1);
        h[j] = h0 | ((unsigned)h1 << 16);
        l[j] = l0 | ((unsigned)l1 << 16);
    }
    *(uint4*)(base + caddr(row, col))       = make_uint4(h[0], h[1], h[2], h[3]);
    *(uint4*)(base + caddr(row, col + 512)) = make_uint4(l[0], l[1], l[2], l[3]);
}
// 4-col variant (col%4==0): 4 shorts contiguous within an 8-col block
__device__ inline void store_split4_c(unsigned short* base, int row, int col,
                                      float4 v) {
    unsigned short h[4], l[4];
    split2(v.x, h[0], l[0]); split2(v.y, h[1], l[1]);
    split2(v.z, h[2], l[2]); split2(v.w, h[3], l[3]);
    uint2 hp, lp;
    hp.x = h[0] | ((unsigned)h[1] << 16); hp.y = h[2] | ((unsigned)h[3] << 16);
    lp.x = l[0] | ((unsigned)l[1] << 16); lp.y = l[2] | ((unsigned)l[3] << 16);
    *(uint2*)(base + caddr(row, col))       = hp;
    *(uint2*)(base + caddr(row, col + 512)) = lp;
}

// bijective XCD-aware block swizzle (m204): contiguous grid bands per XCD
__device__ inline void xcd_swizzle(int& bx, int& by) {
    const int gx = gridDim.x, gy = gridDim.y;
    const int nwg = gx * gy;
    const int orig = by * gx + bx;
    const int q = nwg >> 3, r = nwg & 7;
    const int x8 = orig & 7, i8 = orig >> 3;
    const int wg = (x8 < r ? x8 * (q + 1) : r * (q + 1) + (x8 - r) * q) + i8;
    bx = wg % gx;
    by = wg / gx;
}
// 1-D variant for grids with gridDim.x % 8 == 0: XCD x gets the contiguous
// band [x*n/8, (x+1)*n/8) of work ids -> neighbor blocks (which share K/V or
// tap rows) land on the SAME XCD's L2.
__device__ inline int xcd_swizzle1(int bid, int n) {
    const int q = n >> 3;
    return (bid & 7) * q + (bid >> 3);
}

// ---------------------------------------------------------------------------
__global__ __launch_bounds__(256) void build_pad_split(
    const float* __restrict__ src0, const float* __restrict__ src1,
    const float* __restrict__ front, const float* __restrict__ back,
    unsigned short* __restrict__ d0, unsigned short* __restrict__ d1)
{
    const float* x = blockIdx.z ? src1 : src0;
    unsigned short* xp2 = blockIdx.z ? d1 : d0;
    int idx = blockIdx.x * 256 + threadIdx.x;   // over B*PAD*64
    int c8 = idx & 63;
    int rest = idx >> 6;
    int p = rest % PAD;
    int b = rest / PAD;
    const float* s;
    if (p < WIDTH) {
        s = front + (size_t)p * HID;
    } else if (p < WIDTH + S) {
        s = x + ((size_t)b * S + (p - WIDTH)) * HID;
    } else {
        s = back + (size_t)(p - WIDTH - S) * HID;
    }
    float4 v0 = *(const float4*)(s + c8 * 8);
    float4 v1 = *(const float4*)(s + c8 * 8 + 4);
    store_split8(xp2, b * PAD + p, c8 * 8, v0, v1);
}

// ---------------------------------------------------------------------------
// per-use weight conversion (fallback paths): fp32 [R,HID] -> chunked split
// ---------------------------------------------------------------------------
__global__ __launch_bounds__(256) void conv_w(
    const float* __restrict__ s0, const float* __restrict__ s1,
    unsigned short* __restrict__ w0, unsigned short* __restrict__ w1)
{
    const float* src = blockIdx.z ? s1 : s0;
    unsigned short* dst = blockIdx.z ? w1 : w0;
    int idx = blockIdx.x * 256 + threadIdx.x;   // over R*64
    int c8 = idx & 63;
    int r  = idx >> 6;
    float4 v0 = *(const float4*)(src + (size_t)r * HID + c8 * 8);
    float4 v1 = *(const float4*)(src + (size_t)r * HID + c8 * 8 + 4);
    store_split8(dst, r, c8 * 8, v0, v1);
}

// ---------------------------------------------------------------------------
// one-shot conversion of ALL weights -> w2all [2 dirs][8192 rows] chunked.
// ---------------------------------------------------------------------------
__global__ __launch_bounds__(256) void conv_all(
    const float* __restrict__ fw_lin_w, const float* __restrict__ bw_lin_w,
    const float* __restrict__ fw_hw_w,  const float* __restrict__ bw_hw_w,
    unsigned short* __restrict__ w2all)
{
    int idx = blockIdx.x * 256 + threadIdx.x;   // over 8192*64
    int c8 = idx & 63;
    int r  = idx >> 6;          // 0..8191
    int l  = r >> 12;           // layer
    int rr = r & 4095;
    const float* lin = blockIdx.z ? bw_lin_w : fw_lin_w;
    const float* hw  = blockIdx.z ? bw_hw_w  : fw_hw_w;
    const float* src;
    int drow;
    if (rr < 2048) {
        src  = lin + ((size_t)l * 2048 + rr) * HID;
        drow = blockIdx.z * 8192 + l * 4096 + rr;
    } else {
        int sub  = rr - 2048;
        int i_hw = sub >> 10;
        int rr2  = sub & 1023;
        int c    = rr2 & 511;
        int is_g = rr2 >> 9;
        int p    = ((c >> 4) << 5) + (c & 15) + (is_g << 4);
        src  = hw + ((size_t)l * 2048 + sub) * HID;
        drow = blockIdx.z * 8192 + l * 4096 + 2048 + (i_hw << 10) + p;
    }
    float4 v0 = *(const float4*)(src + c8 * 8);
    float4 v1 = *(const float4*)(src + c8 * 8 + 4);
    store_split8(w2all, drow, c8 * 8, v0, v1);
}

// ===========================================================================
// HYBRID split-bf16 MFMA GEMM (NT), chunked operands (R6/R8-proven).
// A: via LDS 3-slot ring. B: direct global->register, 3-deep static prefetch.
// Ring depth 3 is the optimum: ring-4 (R9) and mixed-depth (R11) both spilled
// to scratch (FETCH/WRITE inflation) and regressed. Per iter: vmcnt(6)
// [certifies A(t),B(t); leaves t+1 in flight] -> s_barrier -> issue
// stageA(t+2)+loadB(t+2) -> 8 ds_read + 16 MFMA. vmcnt(0) only at t=31.
// LDS 24KB; launch_bounds(256,3).
// ===========================================================================
#define GLDS(src, dst) __builtin_amdgcn_global_load_lds(                        \
    (const __attribute__((address_space(1))) void*)(src),                       \
    (__attribute__((address_space(3))) void*)(dst), 16, 0, 0)

#define GEMM_CORE                                                               \
    __shared__ unsigned short Als[3][8 * 512];                                  \
    const int tid  = threadIdx.x;                                               \
    const int wave = tid >> 6;                                                  \
    const int lane = tid & 63;                                                  \
    int bx = blockIdx.x, by = blockIdx.y;                                       \
    xcd_swizzle(bx, by);                                                        \
    const int bm = by * 128;                                                    \
    const int bn = bx * 128;                                                    \
    const int wm = (wave >> 1) * 64;                                            \
    const int wn = (wave & 1) * 64;                                             \
    const unsigned short* SA0 = A  + ((size_t)((bm >> 4) + 2 * wave)     << 14) \
                                   + lane * 8;                                  \
    const unsigned short* SA1 = A  + ((size_t)((bm >> 4) + 2 * wave + 1) << 14) \
                                   + lane * 8;                                  \
    const unsigned short* pb[4];                                                \
    _Pragma("unroll")                                                           \
    for (int j = 0; j < 4; ++j)                                                 \
        pb[j] = Bw + ((size_t)((((bn + wn) >> 4) + j) * 32) << 9) + lane * 8;   \
    f4 acc[4][4] = {};                                                          \
    s8 bfr[3][4];                                                               \
    auto stageA = [&](int slot, int kt) {                                       \
        const int ao = kt << 9;                                                 \
        GLDS(SA0 + ao, &Als[slot][(2 * wave)     * 512]);                       \
        GLDS(SA1 + ao, &Als[slot][(2 * wave + 1) * 512]);                       \
    };                                                                          \
    stageA(0, 0);                                                               \
    _Pragma("unroll")                                                           \
    for (int j = 0; j < 4; ++j) bfr[0][j] = *(const s8*)(pb[j]);                \
    stageA(1, 1);                                                               \
    _Pragma("unroll")                                                           \
    for (int j = 0; j < 4; ++j) bfr[1][j] = *(const s8*)(pb[j] + 512);          \
    _Pragma("unroll")                                                           \
    for (int t = 0; t < 32; ++t) {                                              \
        if (t == 31) asm volatile("s_waitcnt vmcnt(0)" ::: "memory");           \
        else         asm volatile("s_waitcnt vmcnt(6)" ::: "memory");           \
        __builtin_amdgcn_s_barrier();                                           \
        if (t < 30) {                                                           \
            stageA((t + 2) % 3, t + 2);                                         \
            const int bo = ((t + 2) & 15) << 9;                                 \
            _Pragma("unroll")                                                   \
            for (int j = 0; j < 4; ++j)                                         \
                bfr[(t + 2) % 3][j] = *(const s8*)(pb[j] + bo);                 \
        }                                                                       \
        s8 a[4];                                                                \
        _Pragma("unroll")                                                       \
        for (int i = 0; i < 4; ++i)                                             \
            a[i] = *(const s8*)&Als[t % 3][((wave >> 1) * 4 + i) * 512 + lane * 8];\
        __builtin_amdgcn_s_setprio(1);                                          \
        _Pragma("unroll")                                                       \
        for (int i = 0; i < 4; ++i)                                             \
            _Pragma("unroll")                                                   \
            for (int j = 0; j < 4; ++j)                                         \
                acc[i][j] = __builtin_amdgcn_mfma_f32_16x16x32_bf16(            \
                    a[i], bfr[t % 3][j], acc[i][j], 0, 0, 0);                   \
        __builtin_amdgcn_s_setprio(0);                                          \
    }

__global__ __launch_bounds__(256, 3) void gemm_split(
    const unsigned short* __restrict__ A0, const unsigned short* __restrict__ B0,
    const float* __restrict__ bias0, float* __restrict__ C0,
    const unsigned short* __restrict__ A1, const unsigned short* __restrict__ B1,
    const float* __restrict__ bias1, float* __restrict__ C1,
    int N)
{
    const unsigned short* A  = blockIdx.z ? A1 : A0;
    const unsigned short* Bw = blockIdx.z ? B1 : B0;
    const float* bias        = blockIdx.z ? bias1 : bias0;
    float* C                 = blockIdx.z ? C1 : C0;

    GEMM_CORE

    const int col = lane & 15;
    const int rb  = (lane >> 4) * 4;
    #pragma unroll
    for (int j = 0; j < 4; ++j) {
        float bj = bias[bn + wn + j * 16 + col];
        #pragma unroll
        for (int i = 0; i < 4; ++i) {
            size_t base = (size_t)(bm + wm + i * 16 + rb) * N + (bn + wn + j * 16 + col);
            #pragma unroll
            for (int r = 0; r < 4; ++r)
                C[base + (size_t)r * N] = acc[i][j][r] + bj;
        }
    }
}

// ---------------------------------------------------------------------------
// Fused highway GEMM (wall path), same hybrid core. N=1024 permuted weights
// (nl/gate 16-col interleave). Epilogue applies gate; x read from A (chunked).
// ---------------------------------------------------------------------------
__global__ __launch_bounds__(256, 3) void gemm_hw_fused(
    const unsigned short* __restrict__ A0, const unsigned short* __restrict__ B0,
    const float* __restrict__ hwb0, unsigned short* __restrict__ o2_0,
    float* __restrict__ dst0, float* __restrict__ osl0,
    const unsigned short* __restrict__ A1, const unsigned short* __restrict__ B1,
    const float* __restrict__ hwb1, unsigned short* __restrict__ o2_1,
    float* __restrict__ dst1, float* __restrict__ osl1,
    int first)
{
    const unsigned short* A  = blockIdx.z ? A1 : A0;
    const unsigned short* Bw = blockIdx.z ? B1 : B0;
    const float* hwb         = blockIdx.z ? hwb1 : hwb0;
    unsigned short* o2       = blockIdx.z ? o2_1 : o2_0;
    float* dstf              = blockIdx.z ? dst1 : dst0;
    float* osl               = blockIdx.z ? osl1 : osl0;

    GEMM_CORE

    const int col = lane & 15;
    const int rb  = (lane >> 4) * 4;
    #pragma unroll
    for (int jp = 0; jp < 2; ++jp) {
        const int cc = ((bn + wn) >> 1) + jp * 16 + col;   // orig col 0..511
        const float bnl = hwb[cc];
        const float bg  = hwb[512 + cc];
        #pragma unroll
        for (int i = 0; i < 4; ++i) {
            #pragma unroll
            for (int r = 0; r < 4; ++r) {
                const int row = bm + wm + i * 16 + rb + r;
                float nl = acc[i][2 * jp][r] + bnl;
                float g  = acc[i][2 * jp + 1][r] + bg;
                float xv = bf2f(A[caddr(row, cc)])
                         + bf2f(A[caddr(row, cc + 512)]);
                float sg = 1.f / (1.f + __expf(-g));
                float o  = sg * xv + (1.f - sg) * fmaxf(nl, 0.f);
                if (first) {
                    unsigned short hh, ll; split2(o, hh, ll);
                    o2[caddr(row, cc)]       = hh;
                    o2[caddr(row, cc + 512)] = ll;
                } else {
                    dstf[(size_t)row * HID + cc]      = o;
                    osl[(size_t)row * (2 * HID) + cc] = o;
                }
            }
        }
    }
}

// ---------------------------------------------------------------------------
// Banded MHA, wave-parallel softmax+PV. One wave per (b,h,i).
// Lane (s = lane>>4, d = lane&15) owns taps {4m+s} and cols {4d..4d+3}.
// XCD band swizzle keeps consecutive i on one XCD's L2 (R8-proven).
// backward = dir0 + z.
// ---------------------------------------------------------------------------
__global__ __launch_bounds__(256) void banded_attn(
    const float* __restrict__ Q0, const float* __restrict__ Q1,
    unsigned short* __restrict__ O0, unsigned short* __restrict__ O1,
    int dir0)
{
    const float* QKV = blockIdx.z ? Q1 : Q0;
    unsigned short* O2 = blockIdx.z ? O1 : O0;
    int backward = dir0 + blockIdx.z;

    int wg   = xcd_swizzle1(blockIdx.x, gridDim.x);   // gridDim.x % 8 == 0
    int w    = wg * 4 + (threadIdx.x >> 6);
    int lane = threadIdx.x & 63;
    int i  = w % PAD;
    int bh = w / PAD;
    int h  = bh & (NHEADS - 1);
    int b  = bh / NHEADS;

    int jlo, n;
    if (backward) { jlo = i; n = min(WIDTH + 2, PAD - i); }
    else          { jlo = max(0, i - WIDTH - 1); n = i - jlo + 1; }

    const int s = lane >> 4;
    const int d = lane & 15;
    const size_t rowbase = (size_t)(b * PAD) * 1536;
    const int colq = h * DK;

    float4 q4 = *(const float4*)(QKV + rowbase + (size_t)i * 1536 + colq + 4 * d);

    // scores: lane's taps t = 4m+s; invalid taps masked to -1e30
    float sc[5];
    float mx = -1e30f;
    #pragma unroll
    for (int m = 0; m < 5; ++m) {
        int t  = 4 * m + s;
        int tc = t < n ? t : n - 1;
        float4 kv = *(const float4*)(QKV + rowbase + (size_t)(jlo + tc) * 1536
                                     + 512 + colq + 4 * d);
        float p = q4.x * kv.x + q4.y * kv.y + q4.z * kv.z + q4.w * kv.w;
        p += __shfl_xor(p, 1);
        p += __shfl_xor(p, 2);
        p += __shfl_xor(p, 4);
        p += __shfl_xor(p, 8);
        sc[m] = (t < n) ? p * 0.125f : -1e30f;
        mx = fmaxf(mx, sc[m]);
    }
    // global max over s-groups (d fixed)
    mx = fmaxf(mx, __shfl_xor(mx, 16));
    mx = fmaxf(mx, __shfl_xor(mx, 32));

    float e[5];
    float dsum = 0.f;
    #pragma unroll
    for (int m = 0; m < 5; ++m) { e[m] = __expf(sc[m] - mx); dsum += e[m]; }
    dsum += __shfl_xor(dsum, 16);
    dsum += __shfl_xor(dsum, 32);
    float inv = 1.0f / dsum;

    // PV: lane accumulates its taps' V rows (float4 over its col-quad)
    float4 pv = make_float4(0.f, 0.f, 0.f, 0.f);
    #pragma unroll
    for (int m = 0; m < 5; ++m) {
        int t  = 4 * m + s;
        int tc = t < n ? t : n - 1;
        float4 v4 = *(const float4*)(QKV + rowbase + (size_t)(jlo + tc) * 1536
                                     + 1024 + colq + 4 * d);
        pv.x += e[m] * v4.x; pv.y += e[m] * v4.y;
        pv.z += e[m] * v4.z; pv.w += e[m] * v4.w;
    }
    // reduce over s-groups
    pv.x += __shfl_xor(pv.x, 16); pv.y += __shfl_xor(pv.y, 16);
    pv.z += __shfl_xor(pv.z, 16); pv.w += __shfl_xor(pv.w, 16);
    pv.x += __shfl_xor(pv.x, 32); pv.y += __shfl_xor(pv.y, 32);
    pv.z += __shfl_xor(pv.z, 32); pv.w += __shfl_xor(pv.w, 32);

    if (s == 0) {
        float4 o = make_float4(pv.x * inv, pv.y * inv, pv.z * inv, pv.w * inv);
        store_split4_c(O2, b * PAD + i, colq + 4 * d, o);
    }
}

// ---------------------------------------------------------------------------
// rel_combine with the same XCD band swizzle (17 overlapping-row taps ->
// neighbor blocks share ATT rows; keep them on one XCD's L2).
// ---------------------------------------------------------------------------
__global__ __launch_bounds__(256) void rel_combine(
    const float* __restrict__ a0, const float* __restrict__ a1,
    const float* __restrict__ w0, const float* __restrict__ w1,
    unsigned short* __restrict__ f0, unsigned short* __restrict__ f1,
    int off0, int off1)
{
    const float* att = blockIdx.z ? a1 : a0;
    const float* w   = blockIdx.z ? w1 : w0;
    unsigned short* fo2 = blockIdx.z ? f1 : f0;
    int offset = blockIdx.z ? off1 : off0;

    int bid = xcd_swizzle1(blockIdx.x, gridDim.x);    // gridDim.x % 8 == 0
    int idx = bid * 256 + threadIdx.x;                // over B*S*64
    int c8 = idx & 63;
    int rest = idx >> 6;
    int t = rest & (S - 1);
    int b = rest >> 10;

    const float* rowbase = att + (size_t)b * PAD * HID + c8 * 8;
    float4 acc0 = *(const float4*)(rowbase + (size_t)(WIDTH + t) * HID);
    float4 acc1 = *(const float4*)(rowbase + (size_t)(WIDTH + t) * HID + 4);
    #pragma unroll
    for (int k = 0; k <= WIDTH; ++k) {
        float wk = w[k];
        float4 x0 = *(const float4*)(rowbase + (size_t)(offset + k + t) * HID);
        float4 x1 = *(const float4*)(rowbase + (size_t)(offset + k + t) * HID + 4);
        acc0.x += wk * x0.x; acc0.y += wk * x0.y;
        acc0.z += wk * x0.z; acc0.w += wk * x0.w;
        acc1.x += wk * x1.x; acc1.y += wk * x1.y;
        acc1.z += wk * x1.z; acc1.w += wk * x1.w;
    }
    store_split8(fo2, b * S + t, c8 * 8, acc0, acc1);
}

// ---------------------------------------------------------------------------
// standalone highway gate (non-wall fallback only)
// ---------------------------------------------------------------------------
__global__ __launch_bounds__(256) void highway_gate(
    const unsigned short* __restrict__ x0, const unsigned short* __restrict__ x1,
    const float* __restrict__ p0, const float* __restrict__ p1,
    float* __restrict__ of0, float* __restrict__ of1,
    unsigned short* __restrict__ o20, unsigned short* __restrict__ o21,
    float* __restrict__ os0, float* __restrict__ os1)
{
    const unsigned short* x2 = blockIdx.z ? x1 : x0;
    const float* proj        = blockIdx.z ? p1 : p0;
    float* outf              = blockIdx.z ? of1 : of0;
    unsigned short* out2     = blockIdx.z ? o21 : o20;
    float* oslice            = blockIdx.z ? os1 : os0;

    int idx = blockIdx.x * 256 + threadIdx.x;   // over B*S*128
    int c4 = idx & 127;
    int r  = idx >> 7;
    uint2 hp = *(const uint2*)(x2 + caddr(r, c4 * 4));
    uint2 lp = *(const uint2*)(x2 + caddr(r, c4 * 4 + 512));
    float4 xv;
    xv.x = bf2f((unsigned short)(hp.x & 0xffff)) + bf2f((unsigned short)(lp.x & 0xffff));
    xv.y = bf2f((unsigned short)(hp.x >> 16))    + bf2f((unsigned short)(lp.x >> 16));
    xv.z = bf2f((unsigned short)(hp.y & 0xffff)) + bf2f((unsigned short)(lp.y & 0xffff));
    xv.w = bf2f((unsigned short)(hp.y >> 16))    + bf2f((unsigned short)(lp.y >> 16));

    float4 nl = *(const float4*)(proj + (size_t)r * (2 * HID) + c4 * 4);
    float4 g  = *(const float4*)(proj + (size_t)r * (2 * HID) + HID + c4 * 4);
    float4 o;
    float sg;
    sg = 1.f / (1.f + __expf(-g.x)); o.x = sg * xv.x + (1.f - sg) * fmaxf(nl.x, 0.f);
    sg = 1.f / (1.f + __expf(-g.y)); o.y = sg * xv.y + (1.f - sg) * fmaxf(nl.y, 0.f);
    sg = 1.f / (1.f + __expf(-g.z)); o.z = sg * xv.z + (1.f - sg) * fmaxf(nl.z, 0.f);
    sg = 1.f / (1.f + __expf(-g.w)); o.w = sg * xv.w + (1.f - sg) * fmaxf(nl.w, 0.f);
    if (outf)   *(float4*)(outf + (size_t)idx * 4) = o;
    if (out2)   store_split4_c(out2, r, c4 * 4, o);
    if (oslice) *(float4*)(oslice + (size_t)r * (2 * HID) + c4 * 4) = o;
}

// ---------------------------------------------------------------------------
extern "C" void kernel_launch(void* const* d_in, const int* in_sizes, int n_in,
                              void* d_out, int out_size, void* d_ws, size_t ws_size,
                              hipStream_t stream)
{
    const float* inputs   = (const float*)d_in[0];
    const float* fw_lin_w = (const float*)d_in[2];
    const float* fw_lin_b = (const float*)d_in[3];
    const float* bw_lin_w = (const float*)d_in[4];
    const float* bw_lin_b = (const float*)d_in[5];
    const float* fw_hw_w  = (const float*)d_in[6];
    const float* fw_hw_b  = (const float*)d_in[7];
    const float* bw_hw_w  = (const float*)d_in[8];
    const float* bw_hw_b  = (const float*)d_in[9];
    const float* fw_pad   = (const float*)d_in[10];
    const float* bw_pad   = (const float*)d_in[11];
    const float* fw_rel   = (const float*)d_in[12];
    const float* bw_rel   = (const float*)d_in[13];
    float* out = (float*)d_out;
    float* ws  = (float*)d_ws;

    const size_t BSH  = (size_t)B * S * HID;      // 2,097,152 floats
    const size_t QKVF = (size_t)B * PAD * 1536;   // 6,488,064 floats per dir
    const int MP = B * PAD;                       // 4224 (= 33 * 128, 264*16)
    const int MS = B * S;                         // 4096 (= 32 * 128)

    const size_t GROUPED_FLOATS = 2 * QKVF + (2 * (size_t)MP * RS + 2 * (size_t)1536 * RS) / 2;
    const size_t WALL_FLOATS    = 2 * QKVF + (2 * (size_t)MP * RS + (size_t)2 * 8192 * RS) / 2;
    const bool wall    = ws_size >= WALL_FLOATS * 4;
    const bool grouped = wall || ws_size >= GROUPED_FLOATS * 4;
    const int G = grouped ? 2 : 1;

    float* f  = ws;
    float* bk = f + BSH;

    float* QKV[2]; float* ATT[2]; float* HWP[2];
    unsigned short* ACT2[2]; unsigned short* W2[2];
    unsigned short* ACT2B[2] = {nullptr, nullptr};
    unsigned short* w2all = nullptr;
    if (grouped) {
        QKV[0] = ws;             QKV[1] = ws + QKVF;
        float* extra = ws + 2 * BSH;
        ATT[0] = extra;          ATT[1] = extra + (size_t)MP * HID;
        HWP[0] = extra;          HWP[1] = extra + (size_t)MS * 1024;
        // ping buffer for fused hw (aliases ATT/HWP region; dead by hw phase)
        ACT2B[0] = (unsigned short*)extra;
        ACT2B[1] = ACT2B[0] + (size_t)MS * RS;
        unsigned short* a2 = (unsigned short*)(ws + 2 * QKVF);
        ACT2[0] = a2;            ACT2[1] = a2 + (size_t)MP * RS;
        unsigned short* w2 = a2 + 2 * (size_t)MP * RS;
        if (wall) { w2all = w2; W2[0] = W2[1] = nullptr; }
        else      { W2[0] = w2; W2[1] = w2 + (size_t)1536 * RS; }
    } else {
        float* qkvS = bk + BSH;
        QKV[0] = QKV[1] = qkvS;
        ATT[0] = ATT[1] = qkvS;
        HWP[0] = HWP[1] = qkvS;
        unsigned short* a2 = (unsigned short*)(qkvS + QKVF);
        ACT2[0] = ACT2[1] = a2;
        W2[0] = W2[1] = a2 + (size_t)MP * RS;
    }

    if (wall) {
        conv_all<<<dim3(8192 * 64 / 256, 1, 2), 256, 0, stream>>>(
            fw_lin_w, bw_lin_w, fw_hw_w, bw_hw_w, w2all);
    }
    // w2all row offsets per (dir,l): QKV=0, out=1536, hw_i=2048+1024*i
    // (all multiples of 16 rows -> chunked sub-buffer offset == row*RS)
    auto WB = [&](int dir, int l, int seg) -> unsigned short* {
        return w2all + ((size_t)dir * 8192 + (size_t)l * 4096 + seg) * RS;
    };

    for (int l = 0; l < NLAYERS; ++l) {
        const float* LINW[2] = {fw_lin_w + (size_t)l * 4 * HID * HID,
                                bw_lin_w + (size_t)l * 4 * HID * HID};
        const float* LINB[2] = {fw_lin_b + (size_t)l * 4 * HID,
                                bw_lin_b + (size_t)l * 4 * HID};
        const float* HWW[2]  = {fw_hw_w + (size_t)l * NHW * 2 * HID * HID,
                                bw_hw_w + (size_t)l * NHW * 2 * HID * HID};
        const float* HWB[2]  = {fw_hw_b + (size_t)l * NHW * 2 * HID,
                                bw_hw_b + (size_t)l * NHW * 2 * HID};
        const float* RELW[2] = {fw_rel + (size_t)l * (WIDTH + 1),
                                bw_rel + (size_t)l * (WIDTH + 1)};
        const float* front = fw_pad + (size_t)l * WIDTH * HID;
        const float* back  = bw_pad + (size_t)l * WIDTH * HID;
        float* DST[2] = {f, bk};
        float* OSL[2] = {out + (size_t)l * B * S * 2 * HID,
                         out + (size_t)l * B * S * 2 * HID + HID};
        const float* SRC[2] = {(l == 0) ? inputs : f, (l == 0) ? inputs : bk};

        for (int d0 = 0; d0 < 2; d0 += G) {
            const int dB = (G == 2) ? 1 : d0;

            build_pad_split<<<dim3(MP * 64 / 256, 1, G), 256, 0, stream>>>(
                SRC[d0], SRC[dB], front, back, ACT2[0], ACT2[1]);

            unsigned short *wq0, *wq1;
            if (wall) { wq0 = WB(d0, l, 0); wq1 = WB(dB, l, 0); }
            else {
                conv_w<<<dim3(1536 * 64 / 256, 1, G), 256, 0, stream>>>(
                    LINW[d0], LINW[dB], W2[0], W2[1]);
                wq0 = W2[0]; wq1 = W2[1];
            }
            gemm_split<<<dim3(1536 / 128, MP / 128, G), 256, 0, stream>>>(
                ACT2[0], wq0, LINB[d0], QKV[0],
                ACT2[1], wq1, LINB[dB], QKV[1], 1536);

            banded_attn<<<dim3(B * NHEADS * PAD / 4, 1, G), 256, 0, stream>>>(
                QKV[0], QKV[1], ACT2[0], ACT2[1], d0);

            unsigned short *wo0, *wo1;
            if (wall) { wo0 = WB(d0, l, 1536); wo1 = WB(dB, l, 1536); }
            else {
                conv_w<<<dim3(512 * 64 / 256, 1, G), 256, 0, stream>>>(
                    LINW[d0] + 3 * (size_t)HID * HID, LINW[dB] + 3 * (size_t)HID * HID,
                    W2[0], W2[1]);
                wo0 = W2[0]; wo1 = W2[1];
            }
            gemm_split<<<dim3(512 / 128, MP / 128, G), 256, 0, stream>>>(
                ACT2[0], wo0, LINB[d0] + 3 * HID, ATT[0],
                ACT2[1], wo1, LINB[dB] + 3 * HID, ATT[1], 512);

            rel_combine<<<dim3(MS * 64 / 256, 1, G), 256, 0, stream>>>(
                ATT[0], ATT[1], RELW[d0], RELW[dB], ACT2[0], ACT2[1],
                d0 * WIDTH, dB * WIDTH);

            if (wall) {
                // hw0: act2 -> act2b (ping), gate fused
                gemm_hw_fused<<<dim3(1024 / 128, MS / 128, G), 256, 0, stream>>>(
                    ACT2[0], WB(d0, l, 2048), HWB[d0], ACT2B[0], nullptr, nullptr,
                    ACT2[1], WB(dB, l, 2048), HWB[dB], ACT2B[1], nullptr, nullptr, 1);
                // hw1: act2b -> dst + output slice, gate fused
                gemm_hw_fused<<<dim3(1024 / 128, MS / 128, G), 256, 0, stream>>>(
                    ACT2B[0], WB(d0, l, 3072), HWB[d0] + 1024, nullptr, DST[d0], OSL[d0],
                    ACT2B[1], WB(dB, l, 3072), HWB[dB] + 1024, nullptr, DST[dB], OSL[dB], 0);
            } else {
                for (int i = 0; i < NHW; ++i) {
                    conv_w<<<dim3(1024 * 64 / 256, 1, G), 256, 0, stream>>>(
                        HWW[d0] + (size_t)i * 2 * HID * HID,
                        HWW[dB] + (size_t)i * 2 * HID * HID, W2[0], W2[1]);
                    gemm_split<<<dim3(1024 / 128, MS / 128, G), 256, 0, stream>>>(
                        ACT2[0], W2[0], HWB[d0] + (size_t)i * 2 * HID, HWP[0],
                        ACT2[1], W2[1], HWB[dB] + (size_t)i * 2 * HID, HWP[1], 1024);
                    const bool last = (i == NHW - 1);
                    highway_gate<<<dim3(MS * 128 / 256, 1, G), 256, 0, stream>>>(
                        ACT2[0], ACT2[1], HWP[0], HWP[1],
                        last ? DST[d0] : (float*)nullptr,
                        last ? DST[dB] : (float*)nullptr,
                        last ? (unsigned short*)nullptr : ACT2[0],
                        last ? (unsigned short*)nullptr : ACT2[1],
                        last ? OSL[d0] : (float*)nullptr,
                        last ? OSL[dB] : (float*)nullptr);
                }
            }
        }
    }
}